// Round 15
// baseline (16.540 us; speedup 1.0000x reference)
//
#include <hip/hip_runtime.h>
#include <hip/hip_bf16.h>

#define D_MODEL 256
#define D_K 128
#define CH 48           // slow-path staging chunk rows
#define NEG_BF16 ((unsigned short)0xFF7F)   // bf16 -3.39e38; exp() underflows to 0

typedef short bf16x8 __attribute__((ext_vector_type(8)));
typedef float f32x4 __attribute__((ext_vector_type(4)));

// HW RNE conversion (v_cvt_*_bf16_f32) — compiler packs pairs; manual bit-twiddle blocked that (R13 post-mortem)
__device__ inline unsigned short f2bf(float x) {
    __hip_bfloat16 h = __float2bfloat16(x);
    union { __hip_bfloat16 b; unsigned short u; } v; v.b = h;
    return v.u;
}
__device__ inline float bf2f(unsigned short h) {
    union { unsigned u; float f; } v; v.u = ((unsigned)h) << 16; return v.f;
}

// ---- LDS layout (bytes), 512-thread pair blocks. Total 80,896 (1 block/CU) ----
// At  [64][256] bf16, XOR-swizzled rows      : [0, 32768)
// Vb  [64][136] bf16 (aliases At, post-QKV)  : [0, 17408)
// Qb  [64][136] bf16                         : [32768, 50176)
// Kb  [64][136] bf16                         : [50176, 67584)
// S   [64][68]  bf16                         : [67584, 76288)
// rinv f32[64] (ints s0/s1/e during search)  : [76288, 76544)
// csum f32[64]                               : [76544, 76800)
// emb  f32[8][128]                           : [76800, 80896)
#define AT_BYTE(r, c2) (((r) << 9) + ((((c2) << 1)) ^ (((r) & 7) << 4)))
#define QB_OFF 32768
#define KB_OFF 50176
#define S_OFF  67584
#define RINV_OFF 76288
#define CSUM_OFF 76544
#define EMB_OFF  76800

// wave-cooperative lower bound on sorted p: smallest i with p[i] >= val. Walking window (correct for any guess).
__device__ __forceinline__ int wave_lb(const int* __restrict__ p, int stride, int n, int val, int guess) {
    const int lane = threadIdx.x & 63;
    int base = guess - 32;
    while (true) {
        int idx = base + lane;
        int v;
        if (idx < 0)        v = -2147483647 - 1;
        else if (idx >= n)  v = 2147483647;
        else                v = p[(size_t)idx * stride];
        unsigned long long ge = __ballot(v >= val);
        if (ge == 0ULL) { base += 64; continue; }
        int v0 = __shfl(v, 0);
        if (v0 >= val && base > 0) { base -= 63; continue; }
        return base + (__ffsll((unsigned long long)ge) - 1);
    }
}

// two-step: coarse stride-16 probe (covers guess±512 ≈ 5.7σ of boundary drift) refines guess, then walk resolves in ~1 iter
__device__ __forceinline__ int wave_lb2(const int* __restrict__ p, int stride, int n, int val, int guess) {
    const int lane = threadIdx.x & 63;
    int cbase = guess - 512;
    int idx = cbase + lane * 16;
    int v;
    if (idx < 0)        v = -2147483647 - 1;
    else if (idx >= n)  v = 2147483647;
    else                v = p[(size_t)idx * stride];
    unsigned long long ge = __ballot(v >= val);
    int g2;
    if (ge == 0ULL)                  g2 = cbase + 63 * 16 + 32;   // boundary right of window; walk
    else {
        int f = __ffsll((unsigned long long)ge) - 1;
        if (f == 0)                  g2 = cbase;                  // boundary at/left of window; walk
        else                         g2 = cbase + (f - 1) * 16 + 24;  // boundary within 16-row bucket
    }
    return wave_lb(p, stride, n, val, g2);
}

// B-operand fragment for output column cc at k-window k0 from fp32 W (on-the-fly transpose+convert)
__device__ __forceinline__ bf16x8 w_frag(const float* __restrict__ W, int cc, int k0, int g) {
    const float* p = W + (size_t)(k0 + g * 8) * D_K + cc;
    unsigned short t8[8];
    #pragma unroll
    for (int j = 0; j < 8; ++j) t8[j] = f2bf(p[(size_t)j * D_K]);
    return *(const bf16x8*)t8;
}

// QKV tile pass (8 waves): At(LDS) x W(global fp32) -> acc[3][NRT]; ct = wave + cl*8
template<int NRT>
__device__ __forceinline__ void qkv_tiles(
    const unsigned char* lds,
    const float* __restrict__ Wq, const float* __restrict__ Wk, const float* __restrict__ Wv,
    int wave, int lr, int g, f32x4 (&acc)[3][NRT])
{
    #pragma unroll
    for (int cl = 0; cl < 3; ++cl) {
        const int ct = wave + cl * 8;
        const int which = ct >> 3, cc = (ct & 7) * 16 + lr;
        const float* W = which == 0 ? Wq : (which == 1 ? Wk : Wv);
        #pragma unroll
        for (int k0 = 0; k0 < 8; ++k0) {
            bf16x8 bf = w_frag(W, cc, k0 * 32, g);
            #pragma unroll
            for (int rt = 0; rt < NRT; ++rt) {
                bf16x8 af = *(const bf16x8*)(lds + AT_BYTE(rt * 16 + lr, k0 * 32 + g * 8));
                acc[cl][rt] = __builtin_amdgcn_mfma_f32_16x16x32_bf16(af, bf, acc[cl][rt], 0, 0, 0);
            }
        }
    }
}

// ---------------- pair fast path: rows [s, s+mtot), molecule split at c1 ----------------
template<int NRT>
__device__ __forceinline__ void fast_pair(
    const float* __restrict__ A,
    const float* __restrict__ Wq, const float* __restrict__ bq,
    const float* __restrict__ Wk, const float* __restrict__ bk,
    const float* __restrict__ Wv, const float* __restrict__ bv,
    float* __restrict__ out, unsigned char* lds,
    int s, int mtot, int c1, int mol0, int mol1, bool w0, bool w1)
{
    unsigned short* Qb = (unsigned short*)(lds + QB_OFF);
    unsigned short* Kb = (unsigned short*)(lds + KB_OFF);
    unsigned short* Vb = (unsigned short*)(lds);        // aliases At (after barrier)
    unsigned short* S  = (unsigned short*)(lds + S_OFF);
    float* rinv = (float*)(lds + RINV_OFF);
    float* csum = (float*)(lds + CSUM_OFF);
    float* emb  = (float*)(lds + EMB_OFF);

    const int tid = threadIdx.x;
    const int wave = tid >> 6, lane = tid & 63;
    const int lr = lane & 15, g = lane >> 4;

    // ---- stage A rows -> At bf16 (coalesced; zero-pad to NRT*16 rows) ----
    #pragma unroll
    for (int it = 0; it < NRT * 2; ++it) {   // NRT*16 rows * 256 cols / (512 thr * 4)
        int eidx = tid * 4 + it * 2048;
        int r = eidx >> 8, c = eidx & 255;
        float4 a;
        if (r < mtot) a = *(const float4*)&A[(size_t)(s + r) * D_MODEL + c];
        else          a = make_float4(0.f, 0.f, 0.f, 0.f);
        unsigned short o[4] = {f2bf(a.x), f2bf(a.y), f2bf(a.z), f2bf(a.w)};
        *(unsigned long long*)(lds + AT_BYTE(r, c)) = *(const unsigned long long*)o;
    }
    __syncthreads();

    // ---- QKV MFMA ----
    f32x4 acc[3][NRT];
    #pragma unroll
    for (int i = 0; i < 3; ++i)
        #pragma unroll
        for (int j = 0; j < NRT; ++j) acc[i][j] = {0.f, 0.f, 0.f, 0.f};
    qkv_tiles<NRT>(lds, Wq, Wk, Wv, wave, lr, g, acc);
    __syncthreads();   // At reads done; Vb may overwrite

    // ---- write Q,K,V (+bias, Q scaled) to LDS bf16 ----
    const float qs = 0.08838834764831845f;
    #pragma unroll
    for (int cl = 0; cl < 3; ++cl) {
        int ct = wave + cl * 8;
        int which = ct >> 3;
        int col = (ct & 7) * 16 + lr;
        const float* bsrc = which == 0 ? bq : (which == 1 ? bk : bv);
        float bb = bsrc[col];
        float sc = which == 0 ? qs : 1.f;
        unsigned short* dst = which == 0 ? Qb : (which == 1 ? Kb : Vb);
        #pragma unroll
        for (int rt = 0; rt < NRT; ++rt) {
            int rbase = rt * 16 + g * 4;
            #pragma unroll
            for (int r = 0; r < 4; ++r)
                dst[(rbase + r) * 136 + col] = f2bf((acc[cl][rt][r] + bb) * sc);
        }
    }
    __syncthreads();

    // ---- scores via MFMA with same-molecule mask ----
    for (int job = wave; job < NRT * NRT; job += 8) {
        int ti = job / NRT, tj = job % NRT;
        f32x4 sa = {0.f, 0.f, 0.f, 0.f};
        #pragma unroll
        for (int kk = 0; kk < 4; ++kk) {
            bf16x8 qf = *(const bf16x8*)&Qb[(ti * 16 + lr) * 136 + kk * 32 + g * 8];
            bf16x8 kf = *(const bf16x8*)&Kb[(tj * 16 + lr) * 136 + kk * 32 + g * 8];
            sa = __builtin_amdgcn_mfma_f32_16x16x32_bf16(qf, kf, sa, 0, 0, 0);
        }
        int jcol = tj * 16 + lr, ibase = ti * 16 + g * 4;
        bool jside = jcol < c1;
        #pragma unroll
        for (int r = 0; r < 4; ++r) {
            bool same = ((ibase + r) < c1) == jside;
            S[(ibase + r) * 68 + jcol] = same ? f2bf(sa[r]) : NEG_BF16;
        }
    }
    __syncthreads();

    // ---- row softmax: 4 lanes per row (masked entries exp to 0) ----
    {
        int row = tid >> 2, sub = tid & 3;
        if (row < mtot) {
            float mx = -3.4e38f;
            for (int j = sub; j < mtot; j += 4) mx = fmaxf(mx, bf2f(S[row * 68 + j]));
            mx = fmaxf(mx, __shfl_xor(mx, 1));
            mx = fmaxf(mx, __shfl_xor(mx, 2));
            float sum = 0.f;
            for (int j = sub; j < mtot; j += 4) {
                float ev = __expf(bf2f(S[row * 68 + j]) - mx);
                S[row * 68 + j] = f2bf(ev);
                sum += ev;
            }
            sum += __shfl_xor(sum, 1);
            sum += __shfl_xor(sum, 2);
            if (sub == 0) rinv[row] = 1.f / sum;
        }
    }
    __syncthreads();

    // ---- column sums of normalized weights ----
    {
        int col = tid >> 2, sub = tid & 3;
        if (col < mtot) {
            float a = 0.f;
            for (int i = sub; i < mtot; i += 4) a += bf2f(S[i * 68 + col]) * rinv[i];
            a += __shfl_xor(a, 1);
            a += __shfl_xor(a, 2);
            if (sub == 0) csum[col] = a;
        }
    }
    __syncthreads();

    // ---- V-pool: single pass, both molecules; 4-way j-split (R13 fix, isolated) ----
    {
        int d = tid & 127, h = (tid >> 7) & 3;
        float a0 = 0.f, a1 = 0.f;
        for (int j = h; j < mtot; j += 4) {
            float t = csum[j] * bf2f(Vb[j * 136 + d]);
            if (j < c1) a0 += t; else a1 += t;
        }
        emb[h * D_K + d] = a0;
        emb[(4 + h) * D_K + d] = a1;
        __syncthreads();
        if (tid < D_K) {
            if (w0) out[(size_t)mol0 * D_K + tid] =
                emb[tid] + emb[D_K + tid] + emb[2 * D_K + tid] + emb[3 * D_K + tid];
        } else if (tid < 2 * D_K) {
            int d1 = tid - D_K;
            if (w1) out[(size_t)mol1 * D_K + d1] =
                emb[4 * D_K + d1] + emb[5 * D_K + d1] + emb[6 * D_K + d1] + emb[7 * D_K + d1];
        }
    }
}

// dispatch single molecule (m <= 64) through the pair path with an empty second half
__device__ __forceinline__ void run_single(
    const float* __restrict__ A,
    const float* __restrict__ Wq, const float* __restrict__ bq,
    const float* __restrict__ Wk, const float* __restrict__ bk,
    const float* __restrict__ Wv, const float* __restrict__ bv,
    float* __restrict__ out, unsigned char* lds, int s, int m, int mol)
{
    if (m <= 16)      fast_pair<1>(A, Wq, bq, Wk, bk, Wv, bv, out, lds, s, m, m, mol, mol, true, false);
    else if (m <= 32) fast_pair<2>(A, Wq, bq, Wk, bk, Wv, bv, out, lds, s, m, m, mol, mol, true, false);
    else if (m <= 48) fast_pair<3>(A, Wq, bq, Wk, bk, Wv, bv, out, lds, s, m, m, mol, mol, true, false);
    else              fast_pair<4>(A, Wq, bq, Wk, bk, Wv, bv, out, lds, s, m, m, mol, mol, true, false);
}

// streaming slow path for one molecule with m > 64 (statistically never)
__device__ void slow_stream(
    const float* __restrict__ A,
    const float* __restrict__ Wq, const float* __restrict__ bq,
    const float* __restrict__ Wk, const float* __restrict__ bk,
    const float* __restrict__ Wv, const float* __restrict__ bv,
    float* __restrict__ out, unsigned char* lds,
    float* __restrict__ Qw, float* __restrict__ Kw, float* __restrict__ Vw,
    float* __restrict__ ML, int s, int m, int mol, int n)
{
    const int tid = threadIdx.x;
    const int wave = tid >> 6, lane = tid & 63;
    const int lr = lane & 15, g = lane >> 4;
    const float qs = 0.08838834764831845f;
    float* emb = (float*)(lds + EMB_OFF);

    for (int r0 = 0; r0 < m; r0 += CH) {
        for (int it = 0; it < (CH * 256) / 2048; ++it) {   // 6
            int eidx = tid * 4 + it * 2048;
            int r = eidx >> 8, c = eidx & 255;
            float4 a;
            if (r0 + r < m) a = *(const float4*)&A[(size_t)(s + r0 + r) * D_MODEL + c];
            else            a = make_float4(0.f, 0.f, 0.f, 0.f);
            unsigned short o[4] = {f2bf(a.x), f2bf(a.y), f2bf(a.z), f2bf(a.w)};
            *(unsigned long long*)(lds + AT_BYTE(r, c)) = *(const unsigned long long*)o;
        }
        __syncthreads();

        f32x4 acc[3][3];
        #pragma unroll
        for (int i = 0; i < 3; ++i)
            #pragma unroll
            for (int j = 0; j < 3; ++j) acc[i][j] = {0.f, 0.f, 0.f, 0.f};
        qkv_tiles<3>(lds, Wq, Wk, Wv, wave, lr, g, acc);

        #pragma unroll
        for (int cl = 0; cl < 3; ++cl) {
            int ct = wave + cl * 8;
            int which = ct >> 3;
            int col = (ct & 7) * 16 + lr;
            const float* bsrc = which == 0 ? bq : (which == 1 ? bk : bv);
            float bb = bsrc[col];
            float sc = which == 0 ? qs : 1.f;
            float* dst = which == 0 ? Qw : (which == 1 ? Kw : Vw);
            #pragma unroll
            for (int rt = 0; rt < 3; ++rt) {
                int rbase = rt * 16 + g * 4;
                #pragma unroll
                for (int r = 0; r < 4; ++r) {
                    int lrow = rbase + r;
                    if (r0 + lrow < m)
                        dst[(size_t)(s + r0 + lrow) * D_K + col] = (acc[cl][rt][r] + bb) * sc;
                }
            }
        }
        __syncthreads();
    }

    if (tid < D_K) emb[tid] = 0.f;
    float* Mv = ML;
    float* Lv = ML + n;
    __threadfence();
    __syncthreads();

    for (int i = tid; i < m; i += 512) {
        const float4* q = (const float4*)(Qw + (size_t)(s + i) * D_K);
        float mx = -3.4e38f, sum = 0.f;
        for (int j = 0; j < m; ++j) {
            const float4* k = (const float4*)(Kw + (size_t)(s + j) * D_K);
            float sc = 0.f;
            #pragma unroll
            for (int t = 0; t < D_K / 4; ++t) {
                float4 a = q[t], b = k[t];
                sc += a.x * b.x + a.y * b.y + a.z * b.z + a.w * b.w;
            }
            if (sc > mx) { sum = sum * __expf(mx - sc) + 1.f; mx = sc; }
            else         { sum += __expf(sc - mx); }
        }
        Mv[s + i] = mx;
        Lv[s + i] = 1.f / sum;
    }
    __threadfence();
    __syncthreads();

    for (int j = tid; j < m; j += 512) {
        const float4* k = (const float4*)(Kw + (size_t)(s + j) * D_K);
        float cj = 0.f;
        for (int i = 0; i < m; ++i) {
            const float4* q = (const float4*)(Qw + (size_t)(s + i) * D_K);
            float sc = 0.f;
            #pragma unroll
            for (int t = 0; t < D_K / 4; ++t) {
                float4 a = q[t], b = k[t];
                sc += a.x * b.x + a.y * b.y + a.z * b.z + a.w * b.w;
            }
            cj += __expf(sc - Mv[s + i]) * Lv[s + i];
        }
        const float* v = Vw + (size_t)(s + j) * D_K;
        for (int d = 0; d < D_K; ++d) atomicAdd(&emb[d], cj * v[d]);
    }
    __syncthreads();
    if (tid < D_K) out[(size_t)mol * D_K + tid] = emb[tid];
}

// ---------------- single kernel: one block = two consecutive molecules ----------------
__global__ __launch_bounds__(512, 1) void fused_pair(
    const float* __restrict__ A,
    const float* __restrict__ Wq, const float* __restrict__ bq,
    const float* __restrict__ Wk, const float* __restrict__ bk,
    const float* __restrict__ Wv, const float* __restrict__ bv,
    const int* __restrict__ midx,
    float* __restrict__ out,
    float* __restrict__ Qw, float* __restrict__ Kw, float* __restrict__ Vw,
    float* __restrict__ ML, int n, int nmol)
{
    __shared__ __align__(16) unsigned char lds[80896];
    int* se = (int*)(lds + RINV_OFF);   // temp: [0]=s0, [1]=s1, [2]=e

    const int tid = threadIdx.x;
    const int wave = tid >> 6;
    const int mol0 = blockIdx.x * 2;
    const int mol1 = mol0 + 1;
    const bool haveM1 = mol1 < nmol;

    // int64 detection: sorted int64 high words are 0 -> last int32 slot == 0
    const int stride = (midx[n - 1] == 0) ? 2 : 1;

    // ---- segment bounds: waves 0,1,2 search concurrently (two-step: coarse probe + walk) ----
    if (wave < 3) {
        int val = mol0 + wave;
        if (val > nmol) val = nmol;
        int r = wave_lb2(midx, stride, n, val, (int)(((long long)val * n) / nmol));
        if ((tid & 63) == 0) se[wave] = r;
    }
    __syncthreads();
    const int s0 = se[0], s1 = se[1], e = se[2];
    __syncthreads();   // se consumed; rinv area reusable

    const int m0 = s1 - s0, m1 = e - s1, mtot = e - s0;
    const int c1 = m0;

    if (mtot == 0) {
        if (tid < D_K) out[(size_t)mol0 * D_K + tid] = 0.f;
        else if (haveM1 && tid < 2 * D_K) out[(size_t)mol1 * D_K + (tid - D_K)] = 0.f;
        return;
    }

    if (mtot <= 64) {
        if (mtot <= 16)      fast_pair<1>(A, Wq, bq, Wk, bk, Wv, bv, out, lds, s0, mtot, c1, mol0, mol1, true, haveM1);
        else if (mtot <= 32) fast_pair<2>(A, Wq, bq, Wk, bk, Wv, bv, out, lds, s0, mtot, c1, mol0, mol1, true, haveM1);
        else if (mtot <= 48) fast_pair<3>(A, Wq, bq, Wk, bk, Wv, bv, out, lds, s0, mtot, c1, mol0, mol1, true, haveM1);
        else                 fast_pair<4>(A, Wq, bq, Wk, bk, Wv, bv, out, lds, s0, mtot, c1, mol0, mol1, true, haveM1);
        return;
    }

    // ---- rare: pair too large -> per-molecule sequential ----
    if (m0 <= 64) run_single(A, Wq, bq, Wk, bk, Wv, bv, out, lds, s0, m0, mol0);
    else          slow_stream(A, Wq, bq, Wk, bk, Wv, bv, out, lds, Qw, Kw, Vw, ML, s0, m0, mol0, n);
    __syncthreads();
    if (haveM1) {
        if (m1 == 0) { if (tid < D_K) out[(size_t)mol1 * D_K + tid] = 0.f; return; }
        if (m1 <= 64) run_single(A, Wq, bq, Wk, bk, Wv, bv, out, lds, s1, m1, mol1);
        else          slow_stream(A, Wq, bq, Wk, bk, Wv, bv, out, lds, Qw, Kw, Vw, ML, s1, m1, mol1, n);
    }
}

extern "C" void kernel_launch(void* const* d_in, const int* in_sizes, int n_in,
                              void* d_out, int out_size, void* d_ws, size_t ws_size,
                              hipStream_t stream) {
    const float* frag = (const float*)d_in[0];
    const int*   midx = (const int*)d_in[1];
    const float* Wq = (const float*)d_in[2];
    const float* bq = (const float*)d_in[3];
    const float* Wk = (const float*)d_in[4];
    const float* bk = (const float*)d_in[5];
    const float* Wv = (const float*)d_in[6];
    const float* bv = (const float*)d_in[7];
    float* out = (float*)d_out;

    const int n = in_sizes[1];          // 8192
    const int nmol = out_size / D_K;    // 512

    float* Qw = (float*)d_ws;           // slow-path scratch only
    float* Kw = Qw + (size_t)n * D_K;
    float* Vw = Kw + (size_t)n * D_K;
    float* ML = Vw + (size_t)n * D_K;   // 2*n floats

    const int nblocks = (nmol + 1) / 2; // 256
    fused_pair<<<nblocks, 512, 0, stream>>>(frag, Wq, bq, Wk, bk, Wv, bv, midx,
                                            out, Qw, Kw, Vw, ML, n, nmol);
}

// Round 16
// 16.323 us; speedup vs baseline: 1.0133x; 1.0133x over previous
//
#include <hip/hip_runtime.h>
#include <hip/hip_bf16.h>

#define D_MODEL 256
#define D_K 128
#define CH 48           // slow-path staging chunk rows
#define NEG_BF16 ((unsigned short)0xFF7F)   // bf16 -3.39e38; exp() underflows to 0

typedef short bf16x8 __attribute__((ext_vector_type(8)));
typedef float f32x4 __attribute__((ext_vector_type(4)));

// HW RNE conversion (v_cvt_*_bf16_f32) — compiler packs pairs; manual bit-twiddle blocked that (R13 post-mortem)
__device__ inline unsigned short f2bf(float x) {
    __hip_bfloat16 h = __float2bfloat16(x);
    union { __hip_bfloat16 b; unsigned short u; } v; v.b = h;
    return v.u;
}
__device__ inline float bf2f(unsigned short h) {
    union { unsigned u; float f; } v; v.u = ((unsigned)h) << 16; return v.f;
}

// ---- LDS layout (bytes), 512-thread pair blocks. Total 78,848 ----
// At  [64][256] bf16, XOR-swizzled rows      : [0, 32768)
// Vb  [64][136] bf16 (aliases At, post-QKV)  : [0, 17408)
// Qb  [64][136] bf16                         : [32768, 50176)
// Kb  [64][136] bf16                         : [50176, 67584)
// S   [64][68]  bf16                         : [67584, 76288)
// rinv f32[64] (ints s0/s1/e during search)  : [76288, 76544)
// csum f32[64]                               : [76544, 76800)
// emb  f32[4][128]                           : [76800, 78848)
#define AT_BYTE(r, c2) (((r) << 9) + ((((c2) << 1)) ^ (((r) & 7) << 4)))
#define QB_OFF 32768
#define KB_OFF 50176
#define S_OFF  67584
#define RINV_OFF 76288
#define CSUM_OFF 76544
#define EMB_OFF  76800

// wave-cooperative lower bound on sorted p: smallest i with p[i] >= val. Walking window (correct for any guess).
__device__ __forceinline__ int wave_lb(const int* __restrict__ p, int stride, int n, int val, int guess) {
    const int lane = threadIdx.x & 63;
    int base = guess - 32;
    while (true) {
        int idx = base + lane;
        int v;
        if (idx < 0)        v = -2147483647 - 1;
        else if (idx >= n)  v = 2147483647;
        else                v = p[(size_t)idx * stride];
        unsigned long long ge = __ballot(v >= val);
        if (ge == 0ULL) { base += 64; continue; }
        int v0 = __shfl(v, 0);
        if (v0 >= val && base > 0) { base -= 63; continue; }
        return base + (__ffsll((unsigned long long)ge) - 1);
    }
}

// B-operand fragment for output column cc at k-window k0 from fp32 W (on-the-fly transpose+convert)
__device__ __forceinline__ bf16x8 w_frag(const float* __restrict__ W, int cc, int k0, int g) {
    const float* p = W + (size_t)(k0 + g * 8) * D_K + cc;
    unsigned short t8[8];
    #pragma unroll
    for (int j = 0; j < 8; ++j) t8[j] = f2bf(p[(size_t)j * D_K]);
    return *(const bf16x8*)t8;
}

// QKV tile pass (8 waves): At(LDS) x W(global fp32) -> acc[3][NRT]; ct = wave + cl*8
template<int NRT>
__device__ __forceinline__ void qkv_tiles(
    const unsigned char* lds,
    const float* __restrict__ Wq, const float* __restrict__ Wk, const float* __restrict__ Wv,
    int wave, int lr, int g, f32x4 (&acc)[3][NRT])
{
    #pragma unroll
    for (int cl = 0; cl < 3; ++cl) {
        const int ct = wave + cl * 8;
        const int which = ct >> 3, cc = (ct & 7) * 16 + lr;
        const float* W = which == 0 ? Wq : (which == 1 ? Wk : Wv);
        #pragma unroll
        for (int k0 = 0; k0 < 8; ++k0) {
            bf16x8 bf = w_frag(W, cc, k0 * 32, g);
            #pragma unroll
            for (int rt = 0; rt < NRT; ++rt) {
                bf16x8 af = *(const bf16x8*)(lds + AT_BYTE(rt * 16 + lr, k0 * 32 + g * 8));
                acc[cl][rt] = __builtin_amdgcn_mfma_f32_16x16x32_bf16(af, bf, acc[cl][rt], 0, 0, 0);
            }
        }
    }
}

// ---------------- pair fast path: rows [s, s+mtot), molecule split at c1 ----------------
// Masked softmax over the pair's rows; writes out[mol0] (cols < c1) and out[mol1] (cols >= c1).
template<int NRT>
__device__ __forceinline__ void fast_pair(
    const float* __restrict__ A,
    const float* __restrict__ Wq, const float* __restrict__ bq,
    const float* __restrict__ Wk, const float* __restrict__ bk,
    const float* __restrict__ Wv, const float* __restrict__ bv,
    float* __restrict__ out, unsigned char* lds,
    int s, int mtot, int c1, int mol0, int mol1, bool w0, bool w1)
{
    unsigned short* Qb = (unsigned short*)(lds + QB_OFF);
    unsigned short* Kb = (unsigned short*)(lds + KB_OFF);
    unsigned short* Vb = (unsigned short*)(lds);        // aliases At (after barrier)
    unsigned short* S  = (unsigned short*)(lds + S_OFF);
    float* rinv = (float*)(lds + RINV_OFF);
    float* csum = (float*)(lds + CSUM_OFF);
    float* emb  = (float*)(lds + EMB_OFF);

    const int tid = threadIdx.x;
    const int wave = tid >> 6, lane = tid & 63;
    const int lr = lane & 15, g = lane >> 4;

    // ---- stage A rows -> At bf16 (coalesced; zero-pad to NRT*16 rows) ----
    #pragma unroll
    for (int it = 0; it < NRT * 2; ++it) {   // NRT*16 rows * 256 cols / (512 thr * 4)
        int eidx = tid * 4 + it * 2048;
        int r = eidx >> 8, c = eidx & 255;
        float4 a;
        if (r < mtot) a = *(const float4*)&A[(size_t)(s + r) * D_MODEL + c];
        else          a = make_float4(0.f, 0.f, 0.f, 0.f);
        unsigned short o[4] = {f2bf(a.x), f2bf(a.y), f2bf(a.z), f2bf(a.w)};
        *(unsigned long long*)(lds + AT_BYTE(r, c)) = *(const unsigned long long*)o;
    }
    __syncthreads();

    // ---- QKV MFMA ----
    f32x4 acc[3][NRT];
    #pragma unroll
    for (int i = 0; i < 3; ++i)
        #pragma unroll
        for (int j = 0; j < NRT; ++j) acc[i][j] = {0.f, 0.f, 0.f, 0.f};
    qkv_tiles<NRT>(lds, Wq, Wk, Wv, wave, lr, g, acc);
    __syncthreads();   // At reads done; Vb may overwrite

    // ---- write Q,K,V (+bias, Q scaled) to LDS bf16 ----
    const float qs = 0.08838834764831845f;
    #pragma unroll
    for (int cl = 0; cl < 3; ++cl) {
        int ct = wave + cl * 8;
        int which = ct >> 3;
        int col = (ct & 7) * 16 + lr;
        const float* bsrc = which == 0 ? bq : (which == 1 ? bk : bv);
        float bb = bsrc[col];
        float sc = which == 0 ? qs : 1.f;
        unsigned short* dst = which == 0 ? Qb : (which == 1 ? Kb : Vb);
        #pragma unroll
        for (int rt = 0; rt < NRT; ++rt) {
            int rbase = rt * 16 + g * 4;
            #pragma unroll
            for (int r = 0; r < 4; ++r)
                dst[(rbase + r) * 136 + col] = f2bf((acc[cl][rt][r] + bb) * sc);
        }
    }
    __syncthreads();

    // ---- scores via MFMA with same-molecule mask ----
    for (int job = wave; job < NRT * NRT; job += 8) {
        int ti = job / NRT, tj = job % NRT;
        f32x4 sa = {0.f, 0.f, 0.f, 0.f};
        #pragma unroll
        for (int kk = 0; kk < 4; ++kk) {
            bf16x8 qf = *(const bf16x8*)&Qb[(ti * 16 + lr) * 136 + kk * 32 + g * 8];
            bf16x8 kf = *(const bf16x8*)&Kb[(tj * 16 + lr) * 136 + kk * 32 + g * 8];
            sa = __builtin_amdgcn_mfma_f32_16x16x32_bf16(qf, kf, sa, 0, 0, 0);
        }
        int jcol = tj * 16 + lr, ibase = ti * 16 + g * 4;
        bool jside = jcol < c1;
        #pragma unroll
        for (int r = 0; r < 4; ++r) {
            bool same = ((ibase + r) < c1) == jside;
            S[(ibase + r) * 68 + jcol] = same ? f2bf(sa[r]) : NEG_BF16;
        }
    }
    __syncthreads();

    // ---- row softmax: 4 lanes per row (masked entries exp to 0) ----
    {
        int row = tid >> 2, sub = tid & 3;
        if (row < mtot) {
            float mx = -3.4e38f;
            for (int j = sub; j < mtot; j += 4) mx = fmaxf(mx, bf2f(S[row * 68 + j]));
            mx = fmaxf(mx, __shfl_xor(mx, 1));
            mx = fmaxf(mx, __shfl_xor(mx, 2));
            float sum = 0.f;
            for (int j = sub; j < mtot; j += 4) {
                float ev = __expf(bf2f(S[row * 68 + j]) - mx);
                S[row * 68 + j] = f2bf(ev);
                sum += ev;
            }
            sum += __shfl_xor(sum, 1);
            sum += __shfl_xor(sum, 2);
            if (sub == 0) rinv[row] = 1.f / sum;
        }
    }
    __syncthreads();

    // ---- column sums of normalized weights ----
    {
        int col = tid >> 2, sub = tid & 3;
        if (col < mtot) {
            float a = 0.f;
            for (int i = sub; i < mtot; i += 4) a += bf2f(S[i * 68 + col]) * rinv[i];
            a += __shfl_xor(a, 1);
            a += __shfl_xor(a, 2);
            if (sub == 0) csum[col] = a;
        }
    }
    __syncthreads();

    // ---- V-pool: pass A (j<c1 -> mol0), pass B (j>=c1 -> mol1); 4-way j-split ----
    {
        int d = tid & 127, h = tid >> 7;   // h in 0..3
        float a = 0.f;
        for (int j = h; j < c1; j += 4) a += csum[j] * bf2f(Vb[j * 136 + d]);
        emb[h * D_K + d] = a;
        __syncthreads();
        if (w0 && tid < D_K)
            out[(size_t)mol0 * D_K + tid] = emb[tid] + emb[D_K + tid] + emb[2 * D_K + tid] + emb[3 * D_K + tid];
        __syncthreads();
        a = 0.f;
        for (int j = c1 + h; j < mtot; j += 4) a += csum[j] * bf2f(Vb[j * 136 + d]);
        emb[h * D_K + d] = a;
        __syncthreads();
        if (w1 && tid < D_K)
            out[(size_t)mol1 * D_K + tid] = emb[tid] + emb[D_K + tid] + emb[2 * D_K + tid] + emb[3 * D_K + tid];
    }
}

// dispatch single molecule (m <= 64) through the pair path with an empty second half
__device__ __forceinline__ void run_single(
    const float* __restrict__ A,
    const float* __restrict__ Wq, const float* __restrict__ bq,
    const float* __restrict__ Wk, const float* __restrict__ bk,
    const float* __restrict__ Wv, const float* __restrict__ bv,
    float* __restrict__ out, unsigned char* lds, int s, int m, int mol)
{
    if (m <= 16)      fast_pair<1>(A, Wq, bq, Wk, bk, Wv, bv, out, lds, s, m, m, mol, mol, true, false);
    else if (m <= 32) fast_pair<2>(A, Wq, bq, Wk, bk, Wv, bv, out, lds, s, m, m, mol, mol, true, false);
    else if (m <= 48) fast_pair<3>(A, Wq, bq, Wk, bk, Wv, bv, out, lds, s, m, m, mol, mol, true, false);
    else              fast_pair<4>(A, Wq, bq, Wk, bk, Wv, bv, out, lds, s, m, m, mol, mol, true, false);
}

// streaming slow path for one molecule with m > 64 (statistically never)
__device__ void slow_stream(
    const float* __restrict__ A,
    const float* __restrict__ Wq, const float* __restrict__ bq,
    const float* __restrict__ Wk, const float* __restrict__ bk,
    const float* __restrict__ Wv, const float* __restrict__ bv,
    float* __restrict__ out, unsigned char* lds,
    float* __restrict__ Qw, float* __restrict__ Kw, float* __restrict__ Vw,
    float* __restrict__ ML, int s, int m, int mol, int n)
{
    const int tid = threadIdx.x;
    const int wave = tid >> 6, lane = tid & 63;
    const int lr = lane & 15, g = lane >> 4;
    const float qs = 0.08838834764831845f;
    float* emb = (float*)(lds + EMB_OFF);

    for (int r0 = 0; r0 < m; r0 += CH) {
        for (int it = 0; it < (CH * 256) / 2048; ++it) {   // 6
            int eidx = tid * 4 + it * 2048;
            int r = eidx >> 8, c = eidx & 255;
            float4 a;
            if (r0 + r < m) a = *(const float4*)&A[(size_t)(s + r0 + r) * D_MODEL + c];
            else            a = make_float4(0.f, 0.f, 0.f, 0.f);
            unsigned short o[4] = {f2bf(a.x), f2bf(a.y), f2bf(a.z), f2bf(a.w)};
            *(unsigned long long*)(lds + AT_BYTE(r, c)) = *(const unsigned long long*)o;
        }
        __syncthreads();

        f32x4 acc[3][3];
        #pragma unroll
        for (int i = 0; i < 3; ++i)
            #pragma unroll
            for (int j = 0; j < 3; ++j) acc[i][j] = {0.f, 0.f, 0.f, 0.f};
        qkv_tiles<3>(lds, Wq, Wk, Wv, wave, lr, g, acc);

        #pragma unroll
        for (int cl = 0; cl < 3; ++cl) {
            int ct = wave + cl * 8;
            int which = ct >> 3;
            int col = (ct & 7) * 16 + lr;
            const float* bsrc = which == 0 ? bq : (which == 1 ? bk : bv);
            float bb = bsrc[col];
            float sc = which == 0 ? qs : 1.f;
            float* dst = which == 0 ? Qw : (which == 1 ? Kw : Vw);
            #pragma unroll
            for (int rt = 0; rt < 3; ++rt) {
                int rbase = rt * 16 + g * 4;
                #pragma unroll
                for (int r = 0; r < 4; ++r) {
                    int lrow = rbase + r;
                    if (r0 + lrow < m)
                        dst[(size_t)(s + r0 + lrow) * D_K + col] = (acc[cl][rt][r] + bb) * sc;
                }
            }
        }
        __syncthreads();
    }

    if (tid < D_K) emb[tid] = 0.f;
    float* Mv = ML;
    float* Lv = ML + n;
    __threadfence();
    __syncthreads();

    for (int i = tid; i < m; i += 512) {
        const float4* q = (const float4*)(Qw + (size_t)(s + i) * D_K);
        float mx = -3.4e38f, sum = 0.f;
        for (int j = 0; j < m; ++j) {
            const float4* k = (const float4*)(Kw + (size_t)(s + j) * D_K);
            float sc = 0.f;
            #pragma unroll
            for (int t = 0; t < D_K / 4; ++t) {
                float4 a = q[t], b = k[t];
                sc += a.x * b.x + a.y * b.y + a.z * b.z + a.w * b.w;
            }
            if (sc > mx) { sum = sum * __expf(mx - sc) + 1.f; mx = sc; }
            else         { sum += __expf(sc - mx); }
        }
        Mv[s + i] = mx;
        Lv[s + i] = 1.f / sum;
    }
    __threadfence();
    __syncthreads();

    for (int j = tid; j < m; j += 512) {
        const float4* k = (const float4*)(Kw + (size_t)(s + j) * D_K);
        float cj = 0.f;
        for (int i = 0; i < m; ++i) {
            const float4* q = (const float4*)(Qw + (size_t)(s + i) * D_K);
            float sc = 0.f;
            #pragma unroll
            for (int t = 0; t < D_K / 4; ++t) {
                float4 a = q[t], b = k[t];
                sc += a.x * b.x + a.y * b.y + a.z * b.z + a.w * b.w;
            }
            cj += __expf(sc - Mv[s + i]) * Lv[s + i];
        }
        const float* v = Vw + (size_t)(s + j) * D_K;
        for (int d = 0; d < D_K; ++d) atomicAdd(&emb[d], cj * v[d]);
    }
    __syncthreads();
    if (tid < D_K) out[(size_t)mol * D_K + tid] = emb[tid];
}

// ---------------- single kernel: one block = two consecutive molecules ----------------
__global__ __launch_bounds__(512, 1) void fused_pair(
    const float* __restrict__ A,
    const float* __restrict__ Wq, const float* __restrict__ bq,
    const float* __restrict__ Wk, const float* __restrict__ bk,
    const float* __restrict__ Wv, const float* __restrict__ bv,
    const int* __restrict__ midx,
    float* __restrict__ out,
    float* __restrict__ Qw, float* __restrict__ Kw, float* __restrict__ Vw,
    float* __restrict__ ML, int n, int nmol)
{
    __shared__ __align__(16) unsigned char lds[78848];
    int* se = (int*)(lds + RINV_OFF);   // temp: [0]=s0, [1]=s1, [2]=e

    const int tid = threadIdx.x;
    const int wave = tid >> 6;
    const int mol0 = blockIdx.x * 2;
    const int mol1 = mol0 + 1;
    const bool haveM1 = mol1 < nmol;

    // int64 detection: sorted int64 high words are 0 -> last int32 slot == 0
    const int stride = (midx[n - 1] == 0) ? 2 : 1;

    // ---- segment bounds: waves 0,1,2 search concurrently ----
    if (wave < 3) {
        int val = mol0 + wave;
        if (val > nmol) val = nmol;
        int r = wave_lb(midx, stride, n, val, (int)(((long long)val * n) / nmol));
        if ((tid & 63) == 0) se[wave] = r;
    }
    __syncthreads();
    const int s0 = se[0], s1 = se[1], e = se[2];
    // NOTE: no second barrier needed — every thread has read se here, and the first
    // write that can alias it (rinv, after B3 in fast_pair) is ordered behind the
    // staging barrier B1 which every thread passes after this point.

    const int m0 = s1 - s0, m1 = e - s1, mtot = e - s0;
    const int c1 = m0;

    if (mtot == 0) {
        if (tid < D_K) out[(size_t)mol0 * D_K + tid] = 0.f;
        else if (haveM1 && tid < 2 * D_K) out[(size_t)mol1 * D_K + (tid - D_K)] = 0.f;
        return;
    }

    if (mtot <= 64) {
        if (mtot <= 16)      fast_pair<1>(A, Wq, bq, Wk, bk, Wv, bv, out, lds, s0, mtot, c1, mol0, mol1, true, haveM1);
        else if (mtot <= 32) fast_pair<2>(A, Wq, bq, Wk, bk, Wv, bv, out, lds, s0, mtot, c1, mol0, mol1, true, haveM1);
        else if (mtot <= 48) fast_pair<3>(A, Wq, bq, Wk, bk, Wv, bv, out, lds, s0, mtot, c1, mol0, mol1, true, haveM1);
        else                 fast_pair<4>(A, Wq, bq, Wk, bk, Wv, bv, out, lds, s0, mtot, c1, mol0, mol1, true, haveM1);
        return;
    }

    // ---- rare: pair too large -> per-molecule sequential ----
    if (m0 <= 64) run_single(A, Wq, bq, Wk, bk, Wv, bv, out, lds, s0, m0, mol0);
    else          slow_stream(A, Wq, bq, Wk, bk, Wv, bv, out, lds, Qw, Kw, Vw, ML, s0, m0, mol0, n);
    __syncthreads();
    if (haveM1) {
        if (m1 == 0) { if (tid < D_K) out[(size_t)mol1 * D_K + tid] = 0.f; return; }
        if (m1 <= 64) run_single(A, Wq, bq, Wk, bk, Wv, bv, out, lds, s1, m1, mol1);
        else          slow_stream(A, Wq, bq, Wk, bk, Wv, bv, out, lds, Qw, Kw, Vw, ML, s1, m1, mol1, n);
    }
}

extern "C" void kernel_launch(void* const* d_in, const int* in_sizes, int n_in,
                              void* d_out, int out_size, void* d_ws, size_t ws_size,
                              hipStream_t stream) {
    const float* frag = (const float*)d_in[0];
    const int*   midx = (const int*)d_in[1];
    const float* Wq = (const float*)d_in[2];
    const float* bq = (const float*)d_in[3];
    const float* Wk = (const float*)d_in[4];
    const float* bk = (const float*)d_in[5];
    const float* Wv = (const float*)d_in[6];
    const float* bv = (const float*)d_in[7];
    float* out = (float*)d_out;

    const int n = in_sizes[1];          // 8192
    const int nmol = out_size / D_K;    // 512

    float* Qw = (float*)d_ws;           // slow-path scratch only
    float* Kw = Qw + (size_t)n * D_K;
    float* Vw = Kw + (size_t)n * D_K;
    float* ML = Vw + (size_t)n * D_K;   // 2*n floats

    const int nblocks = (nmol + 1) / 2; // 256
    fused_pair<<<nblocks, 512, 0, stream>>>(frag, Wq, bq, Wk, bk, Wv, bv, midx,
                                            out, Qw, Kw, Vw, ML, n, nmol);
}

// Round 17
// 16.255 us; speedup vs baseline: 1.0175x; 1.0042x over previous
//
#include <hip/hip_runtime.h>
#include <hip/hip_bf16.h>

#define D_MODEL 256
#define D_K 128
#define CH 48           // slow-path staging chunk rows
#define NEG_BF16 ((unsigned short)0xFF7F)   // bf16 -3.39e38; exp() underflows to 0

typedef short bf16x8 __attribute__((ext_vector_type(8)));
typedef float f32x4 __attribute__((ext_vector_type(4)));

// HW RNE conversion (v_cvt_*_bf16_f32) — compiler packs pairs; manual bit-twiddle blocked that (R13 post-mortem)
__device__ inline unsigned short f2bf(float x) {
    __hip_bfloat16 h = __float2bfloat16(x);
    union { __hip_bfloat16 b; unsigned short u; } v; v.b = h;
    return v.u;
}
__device__ inline float bf2f(unsigned short h) {
    union { unsigned u; float f; } v; v.u = ((unsigned)h) << 16; return v.f;
}

// ---- LDS layout (bytes), 512-thread pair blocks. Total 78,848 ----
// At  [64][256] bf16, XOR-swizzled rows      : [0, 32768)
// Vb  [64][136] bf16 (aliases At, post-QKV)  : [0, 17408)
// Qb  [64][136] bf16                         : [32768, 50176)
// Kb  [64][136] bf16                         : [50176, 67584)
// S   [64][68]  bf16                         : [67584, 76288)
// rinv f32[64] (ints s0/s1/e during search)  : [76288, 76544)
// csum f32[64]                               : [76544, 76800)
// emb  f32[4][128]                           : [76800, 78848)
#define AT_BYTE(r, c2) (((r) << 9) + ((((c2) << 1)) ^ (((r) & 7) << 4)))
#define QB_OFF 32768
#define KB_OFF 50176
#define S_OFF  67584
#define RINV_OFF 76288
#define CSUM_OFF 76544
#define EMB_OFF  76800

// wave-cooperative lower bound on sorted p: smallest i with p[i] >= val. Walking window (correct for any guess).
__device__ __forceinline__ int wave_lb(const int* __restrict__ p, int stride, int n, int val, int guess) {
    const int lane = threadIdx.x & 63;
    int base = guess - 32;
    while (true) {
        int idx = base + lane;
        int v;
        if (idx < 0)        v = -2147483647 - 1;
        else if (idx >= n)  v = 2147483647;
        else                v = p[(size_t)idx * stride];
        unsigned long long ge = __ballot(v >= val);
        if (ge == 0ULL) { base += 64; continue; }
        int v0 = __shfl(v, 0);
        if (v0 >= val && base > 0) { base -= 63; continue; }
        return base + (__ffsll((unsigned long long)ge) - 1);
    }
}

// B-operand fragment for output column cc at k-window k0 from fp32 W (on-the-fly transpose+convert)
__device__ __forceinline__ bf16x8 w_frag(const float* __restrict__ W, int cc, int k0, int g) {
    const float* p = W + (size_t)(k0 + g * 8) * D_K + cc;
    unsigned short t8[8];
    #pragma unroll
    for (int j = 0; j < 8; ++j) t8[j] = f2bf(p[(size_t)j * D_K]);
    return *(const bf16x8*)t8;
}

// QKV tile pass (8 waves): At(LDS) x W(global fp32) -> acc[3][NRT]; ct = wave + cl*8
template<int NRT>
__device__ __forceinline__ void qkv_tiles(
    const unsigned char* lds,
    const float* __restrict__ Wq, const float* __restrict__ Wk, const float* __restrict__ Wv,
    int wave, int lr, int g, f32x4 (&acc)[3][NRT])
{
    #pragma unroll
    for (int cl = 0; cl < 3; ++cl) {
        const int ct = wave + cl * 8;
        const int which = ct >> 3, cc = (ct & 7) * 16 + lr;
        const float* W = which == 0 ? Wq : (which == 1 ? Wk : Wv);
        #pragma unroll
        for (int k0 = 0; k0 < 8; ++k0) {
            bf16x8 bf = w_frag(W, cc, k0 * 32, g);
            #pragma unroll
            for (int rt = 0; rt < NRT; ++rt) {
                bf16x8 af = *(const bf16x8*)(lds + AT_BYTE(rt * 16 + lr, k0 * 32 + g * 8));
                acc[cl][rt] = __builtin_amdgcn_mfma_f32_16x16x32_bf16(af, bf, acc[cl][rt], 0, 0, 0);
            }
        }
    }
}

// ---------------- pair fast path: rows [s, s+mtot), molecule split at c1 ----------------
// Masked softmax over the pair's rows; writes out[mol0] (cols < c1) and out[mol1] (cols >= c1).
template<int NRT>
__device__ __forceinline__ void fast_pair(
    const float* __restrict__ A,
    const float* __restrict__ Wq, const float* __restrict__ bq,
    const float* __restrict__ Wk, const float* __restrict__ bk,
    const float* __restrict__ Wv, const float* __restrict__ bv,
    float* __restrict__ out, unsigned char* lds,
    int s, int mtot, int c1, int mol0, int mol1, bool w0, bool w1)
{
    unsigned short* Qb = (unsigned short*)(lds + QB_OFF);
    unsigned short* Kb = (unsigned short*)(lds + KB_OFF);
    unsigned short* Vb = (unsigned short*)(lds);        // aliases At (after barrier)
    unsigned short* S  = (unsigned short*)(lds + S_OFF);
    float* rinv = (float*)(lds + RINV_OFF);
    float* csum = (float*)(lds + CSUM_OFF);
    float* emb  = (float*)(lds + EMB_OFF);

    const int tid = threadIdx.x;
    const int wave = tid >> 6, lane = tid & 63;
    const int lr = lane & 15, g = lane >> 4;

    // ---- stage A rows -> At bf16 (coalesced; zero-pad to NRT*16 rows) ----
    #pragma unroll
    for (int it = 0; it < NRT * 2; ++it) {   // NRT*16 rows * 256 cols / (512 thr * 4)
        int eidx = tid * 4 + it * 2048;
        int r = eidx >> 8, c = eidx & 255;
        float4 a;
        if (r < mtot) a = *(const float4*)&A[(size_t)(s + r) * D_MODEL + c];
        else          a = make_float4(0.f, 0.f, 0.f, 0.f);
        unsigned short o[4] = {f2bf(a.x), f2bf(a.y), f2bf(a.z), f2bf(a.w)};
        *(unsigned long long*)(lds + AT_BYTE(r, c)) = *(const unsigned long long*)o;
    }
    __syncthreads();

    // ---- QKV MFMA ----
    f32x4 acc[3][NRT];
    #pragma unroll
    for (int i = 0; i < 3; ++i)
        #pragma unroll
        for (int j = 0; j < NRT; ++j) acc[i][j] = {0.f, 0.f, 0.f, 0.f};
    qkv_tiles<NRT>(lds, Wq, Wk, Wv, wave, lr, g, acc);
    __syncthreads();   // At reads done; Vb may overwrite

    // ---- write Q,K,V (+bias, Q scaled) to LDS bf16 ----
    const float qs = 0.08838834764831845f;
    #pragma unroll
    for (int cl = 0; cl < 3; ++cl) {
        int ct = wave + cl * 8;
        int which = ct >> 3;
        int col = (ct & 7) * 16 + lr;
        const float* bsrc = which == 0 ? bq : (which == 1 ? bk : bv);
        float bb = bsrc[col];
        float sc = which == 0 ? qs : 1.f;
        unsigned short* dst = which == 0 ? Qb : (which == 1 ? Kb : Vb);
        #pragma unroll
        for (int rt = 0; rt < NRT; ++rt) {
            int rbase = rt * 16 + g * 4;
            #pragma unroll
            for (int r = 0; r < 4; ++r)
                dst[(rbase + r) * 136 + col] = f2bf((acc[cl][rt][r] + bb) * sc);
        }
    }
    __syncthreads();

    // ---- scores via MFMA with same-molecule mask ----
    for (int job = wave; job < NRT * NRT; job += 8) {
        int ti = job / NRT, tj = job % NRT;
        f32x4 sa = {0.f, 0.f, 0.f, 0.f};
        #pragma unroll
        for (int kk = 0; kk < 4; ++kk) {
            bf16x8 qf = *(const bf16x8*)&Qb[(ti * 16 + lr) * 136 + kk * 32 + g * 8];
            bf16x8 kf = *(const bf16x8*)&Kb[(tj * 16 + lr) * 136 + kk * 32 + g * 8];
            sa = __builtin_amdgcn_mfma_f32_16x16x32_bf16(qf, kf, sa, 0, 0, 0);
        }
        int jcol = tj * 16 + lr, ibase = ti * 16 + g * 4;
        bool jside = jcol < c1;
        #pragma unroll
        for (int r = 0; r < 4; ++r) {
            bool same = ((ibase + r) < c1) == jside;
            S[(ibase + r) * 68 + jcol] = same ? f2bf(sa[r]) : NEG_BF16;
        }
    }
    __syncthreads();

    // ---- row softmax: 4 lanes per row (masked entries exp to 0) ----
    {
        int row = tid >> 2, sub = tid & 3;
        if (row < mtot) {
            float mx = -3.4e38f;
            for (int j = sub; j < mtot; j += 4) mx = fmaxf(mx, bf2f(S[row * 68 + j]));
            mx = fmaxf(mx, __shfl_xor(mx, 1));
            mx = fmaxf(mx, __shfl_xor(mx, 2));
            float sum = 0.f;
            for (int j = sub; j < mtot; j += 4) {
                float ev = __expf(bf2f(S[row * 68 + j]) - mx);
                S[row * 68 + j] = f2bf(ev);
                sum += ev;
            }
            sum += __shfl_xor(sum, 1);
            sum += __shfl_xor(sum, 2);
            if (sub == 0) rinv[row] = 1.f / sum;
        }
    }
    __syncthreads();

    // ---- column sums of normalized weights ----
    {
        int col = tid >> 2, sub = tid & 3;
        if (col < mtot) {
            float a = 0.f;
            for (int i = sub; i < mtot; i += 4) a += bf2f(S[i * 68 + col]) * rinv[i];
            a += __shfl_xor(a, 1);
            a += __shfl_xor(a, 2);
            if (sub == 0) csum[col] = a;
        }
    }
    __syncthreads();

    // ---- V-pool: pass A (j<c1 -> mol0), pass B (j>=c1 -> mol1); 4-way j-split ----
    {
        int d = tid & 127, h = tid >> 7;   // h in 0..3
        float a = 0.f;
        for (int j = h; j < c1; j += 4) a += csum[j] * bf2f(Vb[j * 136 + d]);
        emb[h * D_K + d] = a;
        __syncthreads();
        if (w0 && tid < D_K)
            out[(size_t)mol0 * D_K + tid] = emb[tid] + emb[D_K + tid] + emb[2 * D_K + tid] + emb[3 * D_K + tid];
        __syncthreads();
        a = 0.f;
        for (int j = c1 + h; j < mtot; j += 4) a += csum[j] * bf2f(Vb[j * 136 + d]);
        emb[h * D_K + d] = a;
        __syncthreads();
        if (w1 && tid < D_K)
            out[(size_t)mol1 * D_K + tid] = emb[tid] + emb[D_K + tid] + emb[2 * D_K + tid] + emb[3 * D_K + tid];
    }
}

// dispatch single molecule (m <= 64) through the pair path with an empty second half
__device__ __forceinline__ void run_single(
    const float* __restrict__ A,
    const float* __restrict__ Wq, const float* __restrict__ bq,
    const float* __restrict__ Wk, const float* __restrict__ bk,
    const float* __restrict__ Wv, const float* __restrict__ bv,
    float* __restrict__ out, unsigned char* lds, int s, int m, int mol)
{
    if (m <= 16)      fast_pair<1>(A, Wq, bq, Wk, bk, Wv, bv, out, lds, s, m, m, mol, mol, true, false);
    else if (m <= 32) fast_pair<2>(A, Wq, bq, Wk, bk, Wv, bv, out, lds, s, m, m, mol, mol, true, false);
    else if (m <= 48) fast_pair<3>(A, Wq, bq, Wk, bk, Wv, bv, out, lds, s, m, m, mol, mol, true, false);
    else              fast_pair<4>(A, Wq, bq, Wk, bk, Wv, bv, out, lds, s, m, m, mol, mol, true, false);
}

// streaming slow path for one molecule with m > 64 (statistically never)
__device__ void slow_stream(
    const float* __restrict__ A,
    const float* __restrict__ Wq, const float* __restrict__ bq,
    const float* __restrict__ Wk, const float* __restrict__ bk,
    const float* __restrict__ Wv, const float* __restrict__ bv,
    float* __restrict__ out, unsigned char* lds,
    float* __restrict__ Qw, float* __restrict__ Kw, float* __restrict__ Vw,
    float* __restrict__ ML, int s, int m, int mol, int n)
{
    const int tid = threadIdx.x;
    const int wave = tid >> 6, lane = tid & 63;
    const int lr = lane & 15, g = lane >> 4;
    const float qs = 0.08838834764831845f;
    float* emb = (float*)(lds + EMB_OFF);

    for (int r0 = 0; r0 < m; r0 += CH) {
        for (int it = 0; it < (CH * 256) / 2048; ++it) {   // 6
            int eidx = tid * 4 + it * 2048;
            int r = eidx >> 8, c = eidx & 255;
            float4 a;
            if (r0 + r < m) a = *(const float4*)&A[(size_t)(s + r0 + r) * D_MODEL + c];
            else            a = make_float4(0.f, 0.f, 0.f, 0.f);
            unsigned short o[4] = {f2bf(a.x), f2bf(a.y), f2bf(a.z), f2bf(a.w)};
            *(unsigned long long*)(lds + AT_BYTE(r, c)) = *(const unsigned long long*)o;
        }
        __syncthreads();

        f32x4 acc[3][3];
        #pragma unroll
        for (int i = 0; i < 3; ++i)
            #pragma unroll
            for (int j = 0; j < 3; ++j) acc[i][j] = {0.f, 0.f, 0.f, 0.f};
        qkv_tiles<3>(lds, Wq, Wk, Wv, wave, lr, g, acc);

        #pragma unroll
        for (int cl = 0; cl < 3; ++cl) {
            int ct = wave + cl * 8;
            int which = ct >> 3;
            int col = (ct & 7) * 16 + lr;
            const float* bsrc = which == 0 ? bq : (which == 1 ? bk : bv);
            float bb = bsrc[col];
            float sc = which == 0 ? qs : 1.f;
            float* dst = which == 0 ? Qw : (which == 1 ? Kw : Vw);
            #pragma unroll
            for (int rt = 0; rt < 3; ++rt) {
                int rbase = rt * 16 + g * 4;
                #pragma unroll
                for (int r = 0; r < 4; ++r) {
                    int lrow = rbase + r;
                    if (r0 + lrow < m)
                        dst[(size_t)(s + r0 + lrow) * D_K + col] = (acc[cl][rt][r] + bb) * sc;
                }
            }
        }
        __syncthreads();
    }

    if (tid < D_K) emb[tid] = 0.f;
    float* Mv = ML;
    float* Lv = ML + n;
    __threadfence();
    __syncthreads();

    for (int i = tid; i < m; i += 512) {
        const float4* q = (const float4*)(Qw + (size_t)(s + i) * D_K);
        float mx = -3.4e38f, sum = 0.f;
        for (int j = 0; j < m; ++j) {
            const float4* k = (const float4*)(Kw + (size_t)(s + j) * D_K);
            float sc = 0.f;
            #pragma unroll
            for (int t = 0; t < D_K / 4; ++t) {
                float4 a = q[t], b = k[t];
                sc += a.x * b.x + a.y * b.y + a.z * b.z + a.w * b.w;
            }
            if (sc > mx) { sum = sum * __expf(mx - sc) + 1.f; mx = sc; }
            else         { sum += __expf(sc - mx); }
        }
        Mv[s + i] = mx;
        Lv[s + i] = 1.f / sum;
    }
    __threadfence();
    __syncthreads();

    for (int j = tid; j < m; j += 512) {
        const float4* k = (const float4*)(Kw + (size_t)(s + j) * D_K);
        float cj = 0.f;
        for (int i = 0; i < m; ++i) {
            const float4* q = (const float4*)(Qw + (size_t)(s + i) * D_K);
            float sc = 0.f;
            #pragma unroll
            for (int t = 0; t < D_K / 4; ++t) {
                float4 a = q[t], b = k[t];
                sc += a.x * b.x + a.y * b.y + a.z * b.z + a.w * b.w;
            }
            cj += __expf(sc - Mv[s + i]) * Lv[s + i];
        }
        const float* v = Vw + (size_t)(s + j) * D_K;
        for (int d = 0; d < D_K; ++d) atomicAdd(&emb[d], cj * v[d]);
    }
    __syncthreads();
    if (tid < D_K) out[(size_t)mol * D_K + tid] = emb[tid];
}

// ---------------- single kernel: one block = two consecutive molecules ----------------
__global__ __launch_bounds__(512, 1) void fused_pair(
    const float* __restrict__ A,
    const float* __restrict__ Wq, const float* __restrict__ bq,
    const float* __restrict__ Wk, const float* __restrict__ bk,
    const float* __restrict__ Wv, const float* __restrict__ bv,
    const int* __restrict__ midx,
    float* __restrict__ out,
    float* __restrict__ Qw, float* __restrict__ Kw, float* __restrict__ Vw,
    float* __restrict__ ML, int n, int nmol)
{
    __shared__ __align__(16) unsigned char lds[78848];
    int* se = (int*)(lds + RINV_OFF);   // temp: [0]=s0, [1]=s1, [2]=e

    const int tid = threadIdx.x;
    const int wave = tid >> 6;
    const int mol0 = blockIdx.x * 2;
    const int mol1 = mol0 + 1;
    const bool haveM1 = mol1 < nmol;

    // int64 detection: sorted int64 high words are 0 -> last int32 slot == 0
    const int stride = (midx[n - 1] == 0) ? 2 : 1;

    // ---- segment bounds: waves 0,1,2 search concurrently ----
    if (wave < 3) {
        int val = mol0 + wave;
        if (val > nmol) val = nmol;
        int r = wave_lb(midx, stride, n, val, (int)(((long long)val * n) / nmol));
        if ((tid & 63) == 0) se[wave] = r;
    }
    __syncthreads();
    const int s0 = se[0], s1 = se[1], e = se[2];
    // NOTE: no second barrier needed — every thread has read se here, and the first
    // write that can alias it (rinv, after B3 in fast_pair) is ordered behind the
    // staging barrier B1 which every thread passes after this point.

    const int m0 = s1 - s0, m1 = e - s1, mtot = e - s0;
    const int c1 = m0;

    if (mtot == 0) {
        if (tid < D_K) out[(size_t)mol0 * D_K + tid] = 0.f;
        else if (haveM1 && tid < 2 * D_K) out[(size_t)mol1 * D_K + (tid - D_K)] = 0.f;
        return;
    }

    if (mtot <= 64) {
        if (mtot <= 16)      fast_pair<1>(A, Wq, bq, Wk, bk, Wv, bv, out, lds, s0, mtot, c1, mol0, mol1, true, haveM1);
        else if (mtot <= 32) fast_pair<2>(A, Wq, bq, Wk, bk, Wv, bv, out, lds, s0, mtot, c1, mol0, mol1, true, haveM1);
        else if (mtot <= 48) fast_pair<3>(A, Wq, bq, Wk, bk, Wv, bv, out, lds, s0, mtot, c1, mol0, mol1, true, haveM1);
        else                 fast_pair<4>(A, Wq, bq, Wk, bk, Wv, bv, out, lds, s0, mtot, c1, mol0, mol1, true, haveM1);
        return;
    }

    // ---- rare: pair too large -> per-molecule sequential ----
    if (m0 <= 64) run_single(A, Wq, bq, Wk, bk, Wv, bv, out, lds, s0, m0, mol0);
    else          slow_stream(A, Wq, bq, Wk, bk, Wv, bv, out, lds, Qw, Kw, Vw, ML, s0, m0, mol0, n);
    __syncthreads();
    if (haveM1) {
        if (m1 == 0) { if (tid < D_K) out[(size_t)mol1 * D_K + tid] = 0.f; return; }
        if (m1 <= 64) run_single(A, Wq, bq, Wk, bk, Wv, bv, out, lds, s1, m1, mol1);
        else          slow_stream(A, Wq, bq, Wk, bk, Wv, bv, out, lds, Qw, Kw, Vw, ML, s1, m1, mol1, n);
    }
}

extern "C" void kernel_launch(void* const* d_in, const int* in_sizes, int n_in,
                              void* d_out, int out_size, void* d_ws, size_t ws_size,
                              hipStream_t stream) {
    const float* frag = (const float*)d_in[0];
    const int*   midx = (const int*)d_in[1];
    const float* Wq = (const float*)d_in[2];
    const float* bq = (const float*)d_in[3];
    const float* Wk = (const float*)d_in[4];
    const float* bk = (const float*)d_in[5];
    const float* Wv = (const float*)d_in[6];
    const float* bv = (const float*)d_in[7];
    float* out = (float*)d_out;

    const int n = in_sizes[1];          // 8192
    const int nmol = out_size / D_K;    // 512

    float* Qw = (float*)d_ws;           // slow-path scratch only
    float* Kw = Qw + (size_t)n * D_K;
    float* Vw = Kw + (size_t)n * D_K;
    float* ML = Vw + (size_t)n * D_K;   // 2*n floats

    const int nblocks = (nmol + 1) / 2; // 256
    fused_pair<<<nblocks, 512, 0, stream>>>(frag, Wq, bq, Wk, bk, Wv, bv, midx,
                                            out, Qw, Kw, Vw, ML, n, nmol);
}